// Round 13
// baseline (1157.274 us; speedup 1.0000x reference)
//
#include <hip/hip_runtime.h>
#include <hip/hip_fp16.h>
#include <cmath>

#define NN 20000
#define EE 500000
#define GG 64
#define TS 8192
#define EPS 1e-5f

__device__ __forceinline__ float softplus_ref(float x) {
    return fmaxf(x, 0.f) + log1pf(__expf(-fabsf(x)));
}
__device__ __forceinline__ float softplus_fast(float x) {
    return fmaxf(x, 0.f) + __logf(1.0f + __expf(-fabsf(x)));
}
__device__ __forceinline__ float sigmoid_fast(float x) {
    return __builtin_amdgcn_rcpf(1.0f + __expf(-x));
}

// gaussian table: g[s][k] = exp(coeff*(d_s - o_k)^2)
__global__ void k_gtab(float* __restrict__ g) {
    int i = blockIdx.x * 256 + threadIdx.x;
    if (i >= TS * 100) return;
    int s = i / 100, k = i - 100 * s;
    float d = s * (6.0f / (TS - 1.0f));
    float o = k * (6.0f / 99.0f);
    float step = 6.0f / 99.0f;
    float coeff = -0.5f / (step * step);
    float df = d - o;
    g[i] = __expf(coeff * df * df);
}

// Nearest-neighbor table, paired channels: Tn[l][s][t] = half2(T[c=t], T[c=t+64])
// 4 s-values per wave, 8 independent accumulators.
__global__ void __launch_bounds__(256) k_build_T(
    const float* __restrict__ g, const float* __restrict__ convW,
    const float* __restrict__ convB, __half2* __restrict__ Tn) {
    int lane = threadIdx.x & 63;
    int wv = __builtin_amdgcn_readfirstlane(threadIdx.x >> 6);
    int l = blockIdx.y;
    int s0 = blockIdx.x * 16 + wv * 4;
    const float* w = convW + ((size_t)l * 228 + 128) * 128;
    const float* g0 = g + (size_t)s0 * 100;
    float b0 = convB[l * 128 + lane], b1 = convB[l * 128 + lane + 64];
    float2 a0 = {b0, b1}, a1 = {b0, b1}, a2 = {b0, b1}, a3 = {b0, b1};
#pragma unroll 4
    for (int k = 0; k < 100; k++) {
        float w0 = w[k * 128 + lane];
        float w1 = w[k * 128 + lane + 64];
        float ga = g0[k], gb = g0[100 + k], gc = g0[200 + k], gd = g0[300 + k];
        a0.x += ga * w0; a0.y += ga * w1;
        a1.x += gb * w0; a1.y += gb * w1;
        a2.x += gc * w0; a2.y += gc * w1;
        a3.x += gd * w0; a3.y += gd * w1;
    }
    Tn[((size_t)l * TS + s0 + 0) * 64 + lane] = __floats2half2_rn(a0.x, a0.y);
    Tn[((size_t)l * TS + s0 + 1) * 64 + lane] = __floats2half2_rn(a1.x, a1.y);
    Tn[((size_t)l * TS + s0 + 2) * 64 + lane] = __floats2half2_rn(a2.x, a2.y);
    Tn[((size_t)l * TS + s0 + 3) * 64 + lane] = __floats2half2_rn(a3.x, a3.y);
}

// Wp[l][k][lane] = (W1[k,lane], W1[k,lane+64], W2[k,lane], W2[k,lane+64])
__global__ void k_prepW(const float* __restrict__ convW, float4* __restrict__ Wp) {
    int lane = threadIdx.x;  // 64
    int k = blockIdx.x;      // 64
    int l = blockIdx.y;      // 6
    const float* W1 = convW + ((size_t)l * 228 + k) * 128;
    const float* W2 = convW + ((size_t)l * 228 + 64 + k) * 128;
    Wp[((size_t)l * 64 + k) * 64 + lane] =
        make_float4(W1[lane], W1[lane + 64], W2[lane], W2[lane + 64]);
}

__global__ void k_embed(const int* __restrict__ an, const float* __restrict__ emb,
                        const float* __restrict__ W, const float* __restrict__ b,
                        float* __restrict__ x) {
    int c = threadIdx.x & 63, nl = threadIdx.x >> 6;
    int n = blockIdx.x * 4 + nl;
    if (n >= NN) return;
    const float* e = emb + (size_t)an[n] * 92;
    float acc = b[c];
#pragma unroll 4
    for (int k = 0; k < 92; k++) acc += e[k] * W[k * 64 + c];
    x[(size_t)n * 64 + c] = acc;
}

__global__ void k_hist(const int* __restrict__ dst, int* __restrict__ counts) {
    int e = blockIdx.x * 256 + threadIdx.x;
    if (e < EE) atomicAdd(&counts[dst[e]], 1);
}

// hierarchical scan: local inclusive per 1024-block
__global__ void k_scan_local(const int* __restrict__ counts, int* __restrict__ rp,
                             int* __restrict__ bsum) {
    __shared__ int buf[1024];
    int b = blockIdx.x, tid = threadIdx.x;
    int i = b * 1024 + tid;
    int val = (i < NN) ? counts[i] : 0;
    buf[tid] = val;
    __syncthreads();
    for (int off = 1; off < 1024; off <<= 1) {
        int t = (tid >= off) ? buf[tid - off] : 0;
        __syncthreads();
        buf[tid] += t;
        __syncthreads();
    }
    if (i < NN) rp[i + 1] = buf[tid];
    if (tid == 1023) bsum[b] = buf[1023];
}

__global__ void k_scan_off(int* __restrict__ bsum, int nb) {
    if (threadIdx.x == 0) {
        int acc = 0;
        for (int b = 0; b < nb; b++) { int v = bsum[b]; bsum[b] = acc; acc += v; }
    }
}

__global__ void k_scan_add(int* __restrict__ rp, const int* __restrict__ bsum) {
    int b = blockIdx.x, tid = threadIdx.x;
    int i = b * 1024 + tid;
    if (i < NN) rp[i + 1] += bsum[b];
    if (b == 0 && tid == 0) rp[0] = 0;
}

// scatter + pack fused: ej[pos] = (src<<13) | j  (dst-sorted order)
__global__ void k_scatter(const int* __restrict__ src, const int* __restrict__ dst,
                          const float* __restrict__ dist, const int* __restrict__ rp,
                          int* __restrict__ cursor, unsigned* __restrict__ ej) {
    int e = blockIdx.x * 256 + threadIdx.x;
    if (e < EE) {
        int d = dst[e];
        int p = atomicAdd(&cursor[d], 1);
        float t = dist[e] * ((TS - 1.0f) / 6.0f);
        int j = (int)(t + 0.5f);
        if (j > TS - 1) j = TS - 1;
        ej[rp[d] + p] = ((unsigned)src[e] << 13) | (unsigned)j;
    }
}

// u,v: 4 nodes per wave, Wp float4 loads, readlane broadcast (layer 0 only)
__global__ void __launch_bounds__(256) k_uv(const float* __restrict__ x,
                                            const float4* __restrict__ Wp,
                                            __half2* __restrict__ up, __half2* __restrict__ vp) {
    int lane = threadIdx.x & 63;
    int wv = __builtin_amdgcn_readfirstlane(threadIdx.x >> 6);
    int n0 = (blockIdx.x * 4 + wv) * 4;
    float xa = x[(size_t)(n0 + 0) * 64 + lane];
    float xb = x[(size_t)(n0 + 1) * 64 + lane];
    float xc = x[(size_t)(n0 + 2) * 64 + lane];
    float xd = x[(size_t)(n0 + 3) * 64 + lane];
    float2 ua = {0, 0}, ub = {0, 0}, uc = {0, 0}, ud = {0, 0};
    float2 va = {0, 0}, vb = {0, 0}, vc = {0, 0}, vd = {0, 0};
#pragma unroll 8
    for (int k = 0; k < 64; k++) {
        float4 w = Wp[k * 64 + lane];
        float ka = __uint_as_float(__builtin_amdgcn_readlane(__float_as_uint(xa), k));
        float kb = __uint_as_float(__builtin_amdgcn_readlane(__float_as_uint(xb), k));
        float kc = __uint_as_float(__builtin_amdgcn_readlane(__float_as_uint(xc), k));
        float kd = __uint_as_float(__builtin_amdgcn_readlane(__float_as_uint(xd), k));
        ua.x += ka * w.x; ua.y += ka * w.y; va.x += ka * w.z; va.y += ka * w.w;
        ub.x += kb * w.x; ub.y += kb * w.y; vb.x += kb * w.z; vb.y += kb * w.w;
        uc.x += kc * w.x; uc.y += kc * w.y; vc.x += kc * w.z; vc.y += kc * w.w;
        ud.x += kd * w.x; ud.y += kd * w.y; vd.x += kd * w.z; vd.y += kd * w.w;
    }
    up[(size_t)(n0 + 0) * 64 + lane] = __floats2half2_rn(ua.x, ua.y);
    up[(size_t)(n0 + 1) * 64 + lane] = __floats2half2_rn(ub.x, ub.y);
    up[(size_t)(n0 + 2) * 64 + lane] = __floats2half2_rn(uc.x, uc.y);
    up[(size_t)(n0 + 3) * 64 + lane] = __floats2half2_rn(ud.x, ud.y);
    vp[(size_t)(n0 + 0) * 64 + lane] = __floats2half2_rn(va.x, va.y);
    vp[(size_t)(n0 + 1) * 64 + lane] = __floats2half2_rn(vb.x, vb.y);
    vp[(size_t)(n0 + 2) * 64 + lane] = __floats2half2_rn(vc.x, vc.y);
    vp[(size_t)(n0 + 3) * 64 + lane] = __floats2half2_rn(vd.x, vd.y);
}

// pass A: BN stats; node-strided waves, 8-deep pipeline; nearest-T single-row
// gather; NON-TEMPORAL z store in dst-sorted order (r11-validated: keeps L2 clean).
__global__ void __launch_bounds__(256) k_stats(
    const __half2* __restrict__ up, const __half2* __restrict__ vp,
    const __half2* __restrict__ Tn, const unsigned* __restrict__ ej,
    const int* __restrict__ rp, float* __restrict__ sums,
    unsigned* __restrict__ zbuf) {
    int lane = threadIdx.x & 63;
    int wv = __builtin_amdgcn_readfirstlane(threadIdx.x >> 6);
    float sx = 0.f, sy = 0.f, qx = 0.f, qy = 0.f;
    for (int i = blockIdx.x * 4 + wv; i < NN; i += gridDim.x * 4) {
        float2 uu = __half22float2(up[(size_t)i * 64 + lane]);
        int rs = __builtin_amdgcn_readfirstlane(rp[i]);
        int re = __builtin_amdgcn_readfirstlane(rp[i + 1]);
        int idx = rs;
        for (; idx + 8 <= re; idx += 8) {
            unsigned e[8];
#pragma unroll
            for (int t = 0; t < 8; t++) e[t] = ej[idx + t];
            __half2 vh[8], th[8];
#pragma unroll
            for (int t = 0; t < 8; t++) {
                vh[t] = vp[(size_t)(e[t] >> 13) * 64 + lane];
                th[t] = Tn[(size_t)(e[t] & 8191u) * 64 + lane];
            }
#pragma unroll
            for (int t = 0; t < 8; t++) {
                float2 vv = __half22float2(vh[t]);
                float2 tt = __half22float2(th[t]);
                float z0 = uu.x + vv.x + tt.x;
                float z1 = uu.y + vv.y + tt.y;
                __half2 zh = __floats2half2_rn(z0, z1);
                __builtin_nontemporal_store(*(unsigned*)&zh,
                                            &zbuf[(size_t)(idx + t) * 64 + lane]);
                sx += z0; qx += z0 * z0;
                sy += z1; qy += z1 * z1;
            }
        }
        for (; idx < re; ++idx) {
            unsigned e = ej[idx];
            float2 vv = __half22float2(vp[(size_t)(e >> 13) * 64 + lane]);
            float2 tt = __half22float2(Tn[(size_t)(e & 8191u) * 64 + lane]);
            float z0 = uu.x + vv.x + tt.x;
            float z1 = uu.y + vv.y + tt.y;
            __half2 zh = __floats2half2_rn(z0, z1);
            __builtin_nontemporal_store(*(unsigned*)&zh, &zbuf[(size_t)idx * 64 + lane]);
            sx += z0; qx += z0 * z0;
            sy += z1; qy += z1 * z1;
        }
    }
    __shared__ float red[4][64][4];
    red[wv][lane][0] = sx; red[wv][lane][1] = sy;
    red[wv][lane][2] = qx; red[wv][lane][3] = qy;
    __syncthreads();
    if (wv == 0) {
        for (int r = 1; r < 4; r++) {
            sx += red[r][lane][0]; sy += red[r][lane][1];
            qx += red[r][lane][2]; qy += red[r][lane][3];
        }
        atomicAdd(&sums[lane], sx);
        atomicAdd(&sums[lane + 64], sy);
        atomicAdd(&sums[128 + lane], qx);
        atomicAdd(&sums[192 + lane], qy);
    }
}

// pass B: stream z (nt loads), inline BN fold, sigmoid*softplus, aggregate;
// LN + residual + softplus epilogue in shuffles; FUSED next-layer u/v GEMM
// (overlaps compute with the memory-bound z stream; kills 5 k_uv launches).
__global__ void __launch_bounds__(256) k_aggz(
    const unsigned* __restrict__ zbuf, const int* __restrict__ rp,
    const float* __restrict__ sums,
    const float* __restrict__ bng, const float* __restrict__ bnb,
    const float* __restrict__ lng, const float* __restrict__ lnb,
    int l, const float* __restrict__ xin, float* __restrict__ xout,
    const float4* __restrict__ WpN, __half2* __restrict__ upO, __half2* __restrict__ vpO) {
    int lane = threadIdx.x & 63;
    int wv = __builtin_amdgcn_readfirstlane(threadIdx.x >> 6);
    int i = blockIdx.x * 4 + wv;
    float mu1 = sums[lane] * (1.0f / EE);
    float var1 = sums[128 + lane] * (1.0f / EE) - mu1 * mu1;
    float A1 = rsqrtf(var1 + EPS) * bng[l * 128 + lane];
    float B1 = bnb[l * 128 + lane] - mu1 * A1;
    float mu2 = sums[64 + lane] * (1.0f / EE);
    float var2 = sums[192 + lane] * (1.0f / EE) - mu2 * mu2;
    float A2 = rsqrtf(var2 + EPS) * bng[l * 128 + 64 + lane];
    float B2 = bnb[l * 128 + 64 + lane] - mu2 * A2;

    float xr = xin[(size_t)i * 64 + lane];
    float acc = 0.f;
    int rs = __builtin_amdgcn_readfirstlane(rp[i]);
    int re = __builtin_amdgcn_readfirstlane(rp[i + 1]);
    int idx = rs;
    for (; idx + 8 <= re; idx += 8) {
        unsigned zr[8];
#pragma unroll
        for (int t = 0; t < 8; t++)
            zr[t] = __builtin_nontemporal_load(&zbuf[(size_t)(idx + t) * 64 + lane]);
#pragma unroll
        for (int t = 0; t < 8; t++) {
            float2 z = __half22float2(*(const __half2*)&zr[t]);
            float z0 = z.x * A1 + B1;
            float z1 = z.y * A2 + B2;
            acc += sigmoid_fast(z0) * softplus_fast(z1);
        }
    }
    for (; idx < re; ++idx) {
        unsigned zrw = __builtin_nontemporal_load(&zbuf[(size_t)idx * 64 + lane]);
        float2 z = __half22float2(*(const __half2*)&zrw);
        float z0 = z.x * A1 + B1;
        float z1 = z.y * A2 + B2;
        acc += sigmoid_fast(z0) * softplus_fast(z1);
    }
    float s = acc;
#pragma unroll
    for (int off = 32; off; off >>= 1) s += __shfl_xor(s, off, 64);
    float mean = s * (1.0f / 64.0f);
    float e0v = acc - mean;
    float vv2 = e0v * e0v;
#pragma unroll
    for (int off = 32; off; off >>= 1) vv2 += __shfl_xor(vv2, off, 64);
    float var = vv2 * (1.0f / 64.0f);
    float h = e0v * rsqrtf(var + EPS) * lng[l * 64 + lane] + lnb[l * 64 + lane];
    float xo = softplus_ref(h + xr);
    xout[(size_t)i * 64 + lane] = xo;

    if (WpN) {  // fused next-layer u,v for this node
        float2 ua = {0.f, 0.f}, va = {0.f, 0.f};
#pragma unroll 8
        for (int k = 0; k < 64; k++) {
            float4 w = WpN[k * 64 + lane];
            float xk = __uint_as_float(__builtin_amdgcn_readlane(__float_as_uint(xo), k));
            ua.x += xk * w.x; ua.y += xk * w.y;
            va.x += xk * w.z; va.y += xk * w.w;
        }
        upO[(size_t)i * 64 + lane] = __floats2half2_rn(ua.x, ua.y);
        vpO[(size_t)i * 64 + lane] = __floats2half2_rn(va.x, va.y);
    }
}

// pass B fallback (ws too small): gather version with nearest-T
__global__ void __launch_bounds__(256) k_agg(
    const __half2* __restrict__ up, const __half2* __restrict__ vp,
    const __half2* __restrict__ Tn, const unsigned* __restrict__ ej,
    const int* __restrict__ rp, const float* __restrict__ sums,
    const float* __restrict__ bng, const float* __restrict__ bnb,
    const float* __restrict__ lng, const float* __restrict__ lnb,
    int l, const float* __restrict__ xin, float* __restrict__ xout) {
    int lane = threadIdx.x & 63;
    int wv = __builtin_amdgcn_readfirstlane(threadIdx.x >> 6);
    int i = blockIdx.x * 4 + wv;
    float mu1 = sums[lane] * (1.0f / EE);
    float var1 = sums[128 + lane] * (1.0f / EE) - mu1 * mu1;
    float A1 = rsqrtf(var1 + EPS) * bng[l * 128 + lane];
    float B1 = bnb[l * 128 + lane] - mu1 * A1;
    float mu2 = sums[64 + lane] * (1.0f / EE);
    float var2 = sums[192 + lane] * (1.0f / EE) - mu2 * mu2;
    float A2 = rsqrtf(var2 + EPS) * bng[l * 128 + 64 + lane];
    float B2 = bnb[l * 128 + 64 + lane] - mu2 * A2;

    float2 uu = __half22float2(up[(size_t)i * 64 + lane]);
    float xr = xin[(size_t)i * 64 + lane];
    float acc = 0.f;
    int rs = __builtin_amdgcn_readfirstlane(rp[i]);
    int re = __builtin_amdgcn_readfirstlane(rp[i + 1]);
    int idx = rs;
    for (; idx + 8 <= re; idx += 8) {
        unsigned e[8];
#pragma unroll
        for (int t = 0; t < 8; t++) e[t] = ej[idx + t];
        __half2 vh[8], th[8];
#pragma unroll
        for (int t = 0; t < 8; t++) {
            vh[t] = vp[(size_t)(e[t] >> 13) * 64 + lane];
            th[t] = Tn[(size_t)(e[t] & 8191u) * 64 + lane];
        }
#pragma unroll
        for (int t = 0; t < 8; t++) {
            float2 vv = __half22float2(vh[t]);
            float2 tt = __half22float2(th[t]);
            float z0 = (uu.x + vv.x + tt.x) * A1 + B1;
            float z1 = (uu.y + vv.y + tt.y) * A2 + B2;
            acc += sigmoid_fast(z0) * softplus_fast(z1);
        }
    }
    for (; idx < re; ++idx) {
        unsigned e = ej[idx];
        float2 vv = __half22float2(vp[(size_t)(e >> 13) * 64 + lane]);
        float2 tt = __half22float2(Tn[(size_t)(e & 8191u) * 64 + lane]);
        float z0 = (uu.x + vv.x + tt.x) * A1 + B1;
        float z1 = (uu.y + vv.y + tt.y) * A2 + B2;
        acc += sigmoid_fast(z0) * softplus_fast(z1);
    }
    float s = acc;
#pragma unroll
    for (int off = 32; off; off >>= 1) s += __shfl_xor(s, off, 64);
    float mean = s * (1.0f / 64.0f);
    float e0v = acc - mean;
    float vv2 = e0v * e0v;
#pragma unroll
    for (int off = 32; off; off >>= 1) vv2 += __shfl_xor(vv2, off, 64);
    float var = vv2 * (1.0f / 64.0f);
    float h = e0v * rsqrtf(var + EPS) * lng[l * 64 + lane] + lnb[l * 64 + lane];
    xout[(size_t)i * 64 + lane] = softplus_ref(h + xr);
}

// batch sorted -> graph row pointers by binary search
__global__ void k_gp(const int* __restrict__ batch, int* __restrict__ gp) {
    int g = threadIdx.x;
    if (g > GG) return;
    int lo = 0, hi = NN;
    while (lo < hi) {
        int mid = (lo + hi) >> 1;
        if (batch[mid] < g) lo = mid + 1; else hi = mid;
    }
    gp[g] = lo;
}

// atomic-free segmented mean-pool
__global__ void k_pool2(const float* __restrict__ x, const int* __restrict__ gp,
                        float* __restrict__ mols) {
    int g = blockIdx.x;
    int lane = threadIdx.x & 63, slot = threadIdx.x >> 6;
    int s0 = gp[g], s1 = gp[g + 1];
    float acc = 0.f;
    for (int n = s0 + slot; n < s1; n += 4) acc += x[(size_t)n * 64 + lane];
    __shared__ float red[4][64];
    red[slot][lane] = acc;
    __syncthreads();
    if (slot == 0) {
        float a = red[0][lane] + red[1][lane] + red[2][lane] + red[3][lane];
        float cc = fmaxf((float)(s1 - s0), 1.0f);
        mols[g * 64 + lane] = a / cc;
    }
}

__global__ void k_mlp(const float* __restrict__ mols,
                      const float* __restrict__ fc1W, const float* __restrict__ fc1b,
                      const float* __restrict__ fcsW, const float* __restrict__ fcsb,
                      const float* __restrict__ outW, const float* __restrict__ outb,
                      float* __restrict__ y) {
    int g = blockIdx.x, t = threadIdx.x; // 128 threads
    __shared__ float m[64];
    __shared__ float h[128];
    __shared__ float rbuf[128];
    if (t < 64) m[t] = mols[g * 64 + t];
    __syncthreads();
    float a = fc1b[t];
#pragma unroll 4
    for (int k = 0; k < 64; k++) a += m[k] * fc1W[k * 128 + t];
    h[t] = softplus_ref(a);
    __syncthreads();
    for (int i = 0; i < 3; i++) {
        float b = fcsb[i * 128 + t];
#pragma unroll 4
        for (int k = 0; k < 128; k++) b += h[k] * fcsW[((size_t)i * 128 + k) * 128 + t];
        __syncthreads();
        h[t] = softplus_ref(b);
        __syncthreads();
    }
    rbuf[t] = h[t] * outW[t];
    __syncthreads();
    if (t < 64) {
        float s2 = rbuf[t] + rbuf[t + 64];
#pragma unroll
        for (int off = 32; off; off >>= 1) s2 += __shfl_xor(s2, off, 64);
        if (t == 0) y[g] = s2 + outb[0];
    }
}

extern "C" void kernel_launch(void* const* d_in, const int* in_sizes, int n_in,
                              void* d_out, int out_size, void* d_ws, size_t ws_size,
                              hipStream_t stream) {
    const int*   an    = (const int*)d_in[0];
    const int*   nbr   = (const int*)d_in[1];
    const float* dist  = (const float*)d_in[2];
    const int*   batch = (const int*)d_in[3];
    const float* emb   = (const float*)d_in[4];
    const float* nucW  = (const float*)d_in[5];
    const float* nucB  = (const float*)d_in[6];
    const float* convW = (const float*)d_in[7];
    const float* convB = (const float*)d_in[8];
    const float* bng   = (const float*)d_in[9];
    const float* bnb   = (const float*)d_in[10];
    const float* lng   = (const float*)d_in[11];
    const float* lnb   = (const float*)d_in[12];
    const float* fc1W  = (const float*)d_in[13];
    const float* fc1b  = (const float*)d_in[14];
    const float* fcsW  = (const float*)d_in[15];
    const float* fcsb  = (const float*)d_in[16];
    const float* outW  = (const float*)d_in[17];
    const float* outb  = (const float*)d_in[18];
    const int* srcI = nbr;
    const int* dstI = nbr + EE;

    char* base = (char*)d_ws;
    size_t off = 0;
    auto alloc = [&](size_t b) { size_t r = off; off += (b + 255) & ~(size_t)255; return r; };
    float*    gtab   = (float*)(base + alloc((size_t)TS * 100 * 4));
    __half2*  Tall   = (__half2*)(base + alloc((size_t)6 * TS * 64 * 4));
    float4*   Wp     = (float4*)(base + alloc((size_t)6 * 64 * 64 * 16));
    float*    x0     = (float*)(base + alloc((size_t)NN * 64 * 4));
    float*    x1     = (float*)(base + alloc((size_t)NN * 64 * 4));
    __half2*  up     = (__half2*)(base + alloc((size_t)NN * 64 * 4));
    __half2*  vp     = (__half2*)(base + alloc((size_t)NN * 64 * 4));
    float*    sums6  = (float*)(base + alloc((size_t)6 * 256 * 4));
    int*      counts = (int*)(base + alloc((size_t)NN * 4));
    int*      cursor = (int*)(base + alloc((size_t)NN * 4));
    int*      rp     = (int*)(base + alloc((size_t)(NN + 1) * 4));
    int*      bsum   = (int*)(base + alloc(64 * 4));
    unsigned* ej     = (unsigned*)(base + alloc((size_t)EE * 4));
    float*    mols   = (float*)(base + alloc((size_t)GG * 64 * 4));
    int*      gp     = (int*)(base + alloc((size_t)(GG + 1) * 4));
    size_t zbytes = (size_t)EE * 64 * 4;   // 128 MB fp16 channel-pairs
    unsigned* zbuf = nullptr;
    if (off + zbytes <= ws_size) zbuf = (unsigned*)(base + alloc(zbytes));

    hipMemsetAsync(counts, 0, (size_t)NN * 4, stream);
    hipMemsetAsync(cursor, 0, (size_t)NN * 4, stream);
    hipMemsetAsync(sums6, 0, (size_t)6 * 256 * 4, stream);

    k_gtab<<<(TS * 100 + 255) / 256, 256, 0, stream>>>(gtab);
    k_build_T<<<dim3(TS / 16, 6), 256, 0, stream>>>(gtab, convW, convB, Tall);
    k_prepW<<<dim3(64, 6), 64, 0, stream>>>(convW, Wp);
    k_embed<<<(NN + 3) / 4, 256, 0, stream>>>(an, emb, nucW, nucB, x0);
    k_hist<<<(EE + 255) / 256, 256, 0, stream>>>(dstI, counts);
    const int NB = (NN + 1023) / 1024;
    k_scan_local<<<NB, 1024, 0, stream>>>(counts, rp, bsum);
    k_scan_off<<<1, 64, 0, stream>>>(bsum, NB);
    k_scan_add<<<NB, 1024, 0, stream>>>(rp, bsum);
    k_scatter<<<(EE + 255) / 256, 256, 0, stream>>>(srcI, dstI, dist, rp, cursor, ej);
    k_gp<<<1, 128, 0, stream>>>(batch, gp);

    float* xin = x0;
    float* xout = x1;
    if (zbuf) {
        k_uv<<<NN / 16, 256, 0, stream>>>(xin, Wp, up, vp);   // layer 0 u,v
        for (int l = 0; l < 6; l++) {
            const __half2* Tnl = Tall + (size_t)l * TS * 64;
            float* sums = sums6 + (size_t)l * 256;
            k_stats<<<2048, 256, 0, stream>>>(up, vp, Tnl, ej, rp, sums, zbuf);
            const float4* WpN = (l < 5) ? (Wp + (size_t)(l + 1) * 64 * 64) : nullptr;
            k_aggz<<<NN / 4, 256, 0, stream>>>(zbuf, rp, sums,
                                               bng, bnb, lng, lnb, l, xin, xout,
                                               WpN, up, vp);
            float* tmp = xin; xin = xout; xout = tmp;
        }
    } else {
        for (int l = 0; l < 6; l++) {
            k_uv<<<NN / 16, 256, 0, stream>>>(xin, Wp + (size_t)l * 64 * 64, up, vp);
            const __half2* Tnl = Tall + (size_t)l * TS * 64;
            float* sums = sums6 + (size_t)l * 256;
            k_stats<<<2048, 256, 0, stream>>>(up, vp, Tnl, ej, rp, sums, zbuf);
            k_agg<<<NN / 4, 256, 0, stream>>>(up, vp, Tnl, ej, rp, sums,
                                              bng, bnb, lng, lnb, l, xin, xout);
            float* tmp = xin; xin = xout; xout = tmp;
        }
    }
    k_pool2<<<GG, 256, 0, stream>>>(xin, gp, mols);
    k_mlp<<<GG, 128, 0, stream>>>(mols, fc1W, fc1b, fcsW, fcsb, outW, outb, (float*)d_out);
}

// Round 15
// 1034.372 us; speedup vs baseline: 1.1188x; 1.1188x over previous
//
#include <hip/hip_runtime.h>
#include <hip/hip_fp16.h>
#include <cmath>

#define NN 20000
#define EE 500000
#define GG 64
#define TS 8192
#define EPS 1e-5f

__device__ __forceinline__ float softplus_ref(float x) {
    return fmaxf(x, 0.f) + log1pf(__expf(-fabsf(x)));
}
__device__ __forceinline__ float softplus_fast(float x) {
    return fmaxf(x, 0.f) + __logf(1.0f + __expf(-fabsf(x)));
}
__device__ __forceinline__ float sigmoid_fast(float x) {
    return __builtin_amdgcn_rcpf(1.0f + __expf(-x));
}

// z pair layout: dword index of edge `idx`, lane `lane`:
//   (idx>>1)*128 + lane*2 + (idx&1)   — consecutive edge pair adjacent per lane
__device__ __forceinline__ size_t zaddr(int idx, int lane) {
    return (size_t)(idx >> 1) * 128 + lane * 2 + (idx & 1);
}

// gaussian table: g[s][k] = exp(coeff*(d_s - o_k)^2)
__global__ void k_gtab(float* __restrict__ g) {
    int i = blockIdx.x * 256 + threadIdx.x;
    if (i >= TS * 100) return;
    int s = i / 100, k = i - 100 * s;
    float d = s * (6.0f / (TS - 1.0f));
    float o = k * (6.0f / 99.0f);
    float step = 6.0f / 99.0f;
    float coeff = -0.5f / (step * step);
    float df = d - o;
    g[i] = __expf(coeff * df * df);
}

// Nearest-neighbor table, paired channels: Tn[l][s][t] = half2(T[c=t], T[c=t+64])
__global__ void __launch_bounds__(256) k_build_T(
    const float* __restrict__ g, const float* __restrict__ convW,
    const float* __restrict__ convB, __half2* __restrict__ Tn) {
    int lane = threadIdx.x & 63;
    int wv = __builtin_amdgcn_readfirstlane(threadIdx.x >> 6);
    int l = blockIdx.y;
    int s0 = blockIdx.x * 16 + wv * 4;
    const float* w = convW + ((size_t)l * 228 + 128) * 128;
    const float* g0 = g + (size_t)s0 * 100;
    float b0 = convB[l * 128 + lane], b1 = convB[l * 128 + lane + 64];
    float2 a0 = {b0, b1}, a1 = {b0, b1}, a2 = {b0, b1}, a3 = {b0, b1};
#pragma unroll 4
    for (int k = 0; k < 100; k++) {
        float w0 = w[k * 128 + lane];
        float w1 = w[k * 128 + lane + 64];
        float ga = g0[k], gb = g0[100 + k], gc = g0[200 + k], gd = g0[300 + k];
        a0.x += ga * w0; a0.y += ga * w1;
        a1.x += gb * w0; a1.y += gb * w1;
        a2.x += gc * w0; a2.y += gc * w1;
        a3.x += gd * w0; a3.y += gd * w1;
    }
    Tn[((size_t)l * TS + s0 + 0) * 64 + lane] = __floats2half2_rn(a0.x, a0.y);
    Tn[((size_t)l * TS + s0 + 1) * 64 + lane] = __floats2half2_rn(a1.x, a1.y);
    Tn[((size_t)l * TS + s0 + 2) * 64 + lane] = __floats2half2_rn(a2.x, a2.y);
    Tn[((size_t)l * TS + s0 + 3) * 64 + lane] = __floats2half2_rn(a3.x, a3.y);
}

// Wp[l][k][lane] = (W1[k,lane], W1[k,lane+64], W2[k,lane], W2[k,lane+64])
__global__ void k_prepW(const float* __restrict__ convW, float4* __restrict__ Wp) {
    int lane = threadIdx.x;  // 64
    int k = blockIdx.x;      // 64
    int l = blockIdx.y;      // 6
    const float* W1 = convW + ((size_t)l * 228 + k) * 128;
    const float* W2 = convW + ((size_t)l * 228 + 64 + k) * 128;
    Wp[((size_t)l * 64 + k) * 64 + lane] =
        make_float4(W1[lane], W1[lane + 64], W2[lane], W2[lane + 64]);
}

__global__ void k_embed(const int* __restrict__ an, const float* __restrict__ emb,
                        const float* __restrict__ W, const float* __restrict__ b,
                        float* __restrict__ x) {
    int c = threadIdx.x & 63, nl = threadIdx.x >> 6;
    int n = blockIdx.x * 4 + nl;
    if (n >= NN) return;
    const float* e = emb + (size_t)an[n] * 92;
    float acc = b[c];
#pragma unroll 4
    for (int k = 0; k < 92; k++) acc += e[k] * W[k * 64 + c];
    x[(size_t)n * 64 + c] = acc;
}

__global__ void k_hist(const int* __restrict__ dst, int* __restrict__ counts) {
    int e = blockIdx.x * 256 + threadIdx.x;
    if (e < EE) atomicAdd(&counts[dst[e]], 1);
}

__global__ void k_scan_local(const int* __restrict__ counts, int* __restrict__ rp,
                             int* __restrict__ bsum) {
    __shared__ int buf[1024];
    int b = blockIdx.x, tid = threadIdx.x;
    int i = b * 1024 + tid;
    int val = (i < NN) ? counts[i] : 0;
    buf[tid] = val;
    __syncthreads();
    for (int off = 1; off < 1024; off <<= 1) {
        int t = (tid >= off) ? buf[tid - off] : 0;
        __syncthreads();
        buf[tid] += t;
        __syncthreads();
    }
    if (i < NN) rp[i + 1] = buf[tid];
    if (tid == 1023) bsum[b] = buf[1023];
}

__global__ void k_scan_off(int* __restrict__ bsum, int nb) {
    if (threadIdx.x == 0) {
        int acc = 0;
        for (int b = 0; b < nb; b++) { int v = bsum[b]; bsum[b] = acc; acc += v; }
    }
}

__global__ void k_scan_add(int* __restrict__ rp, const int* __restrict__ bsum) {
    int b = blockIdx.x, tid = threadIdx.x;
    int i = b * 1024 + tid;
    if (i < NN) rp[i + 1] += bsum[b];
    if (b == 0 && tid == 0) rp[0] = 0;
}

// scatter + pack fused: ej[pos] = (src<<13) | j  (dst-sorted order)
__global__ void k_scatter(const int* __restrict__ src, const int* __restrict__ dst,
                          const float* __restrict__ dist, const int* __restrict__ rp,
                          int* __restrict__ cursor, unsigned* __restrict__ ej) {
    int e = blockIdx.x * 256 + threadIdx.x;
    if (e < EE) {
        int d = dst[e];
        int p = atomicAdd(&cursor[d], 1);
        float t = dist[e] * ((TS - 1.0f) / 6.0f);
        int j = (int)(t + 0.5f);
        if (j > TS - 1) j = TS - 1;
        ej[rp[d] + p] = ((unsigned)src[e] << 13) | (unsigned)j;
    }
}

// u,v: 4 nodes per wave, Wp float4 loads, readlane broadcast
__global__ void __launch_bounds__(256) k_uv(const float* __restrict__ x,
                                            const float4* __restrict__ Wp,
                                            __half2* __restrict__ up, __half2* __restrict__ vp) {
    int lane = threadIdx.x & 63;
    int wv = __builtin_amdgcn_readfirstlane(threadIdx.x >> 6);
    int n0 = (blockIdx.x * 4 + wv) * 4;
    float xa = x[(size_t)(n0 + 0) * 64 + lane];
    float xb = x[(size_t)(n0 + 1) * 64 + lane];
    float xc = x[(size_t)(n0 + 2) * 64 + lane];
    float xd = x[(size_t)(n0 + 3) * 64 + lane];
    float2 ua = {0, 0}, ub = {0, 0}, uc = {0, 0}, ud = {0, 0};
    float2 va = {0, 0}, vb = {0, 0}, vc = {0, 0}, vd = {0, 0};
#pragma unroll 8
    for (int k = 0; k < 64; k++) {
        float4 w = Wp[k * 64 + lane];
        float ka = __uint_as_float(__builtin_amdgcn_readlane(__float_as_uint(xa), k));
        float kb = __uint_as_float(__builtin_amdgcn_readlane(__float_as_uint(xb), k));
        float kc = __uint_as_float(__builtin_amdgcn_readlane(__float_as_uint(xc), k));
        float kd = __uint_as_float(__builtin_amdgcn_readlane(__float_as_uint(xd), k));
        ua.x += ka * w.x; ua.y += ka * w.y; va.x += ka * w.z; va.y += ka * w.w;
        ub.x += kb * w.x; ub.y += kb * w.y; vb.x += kb * w.z; vb.y += kb * w.w;
        uc.x += kc * w.x; uc.y += kc * w.y; vc.x += kc * w.z; vc.y += kc * w.w;
        ud.x += kd * w.x; ud.y += kd * w.y; vd.x += kd * w.z; vd.y += kd * w.w;
    }
    up[(size_t)(n0 + 0) * 64 + lane] = __floats2half2_rn(ua.x, ua.y);
    up[(size_t)(n0 + 1) * 64 + lane] = __floats2half2_rn(ub.x, ub.y);
    up[(size_t)(n0 + 2) * 64 + lane] = __floats2half2_rn(uc.x, uc.y);
    up[(size_t)(n0 + 3) * 64 + lane] = __floats2half2_rn(ud.x, ud.y);
    vp[(size_t)(n0 + 0) * 64 + lane] = __floats2half2_rn(va.x, va.y);
    vp[(size_t)(n0 + 1) * 64 + lane] = __floats2half2_rn(vb.x, vb.y);
    vp[(size_t)(n0 + 2) * 64 + lane] = __floats2half2_rn(vc.x, vc.y);
    vp[(size_t)(n0 + 3) * 64 + lane] = __floats2half2_rn(vd.x, vd.y);
}

__device__ __forceinline__ float z_of(const __half2* vp, const __half2* Tn,
                                      unsigned e, int lane, float2 uu, float& z1out) {
    float2 vv = __half22float2(vp[(size_t)(e >> 13) * 64 + lane]);
    float2 tt = __half22float2(Tn[(size_t)(e & 8191u) * 64 + lane]);
    z1out = uu.y + vv.y + tt.y;
    return uu.x + vv.x + tt.x;
}

__device__ __forceinline__ unsigned long long pack64(unsigned lo, unsigned hi) {
    return (unsigned long long)lo | ((unsigned long long)hi << 32);
}

// pass A: BN stats; node-strided waves, 8-deep pipeline; nearest-T single-row
// gather; nt z store in PAIR layout (64-bit store per 2 edges).
__global__ void __launch_bounds__(256) k_stats(
    const __half2* __restrict__ up, const __half2* __restrict__ vp,
    const __half2* __restrict__ Tn, const unsigned* __restrict__ ej,
    const int* __restrict__ rp, float* __restrict__ sums,
    unsigned* __restrict__ zbuf) {
    int lane = threadIdx.x & 63;
    int wv = __builtin_amdgcn_readfirstlane(threadIdx.x >> 6);
    float sx = 0.f, sy = 0.f, qx = 0.f, qy = 0.f;
    for (int i = blockIdx.x * 4 + wv; i < NN; i += gridDim.x * 4) {
        float2 uu = __half22float2(up[(size_t)i * 64 + lane]);
        int rs = __builtin_amdgcn_readfirstlane(rp[i]);
        int re = __builtin_amdgcn_readfirstlane(rp[i + 1]);
        int idx = rs;
        if (idx < re && (idx & 1)) {  // peel to even alignment
            float z1, z0 = z_of(vp, Tn, ej[idx], lane, uu, z1);
            __half2 zh = __floats2half2_rn(z0, z1);
            __builtin_nontemporal_store(*(unsigned*)&zh, &zbuf[zaddr(idx, lane)]);
            sx += z0; qx += z0 * z0; sy += z1; qy += z1 * z1;
            idx++;
        }
        for (; idx + 8 <= re; idx += 8) {
            unsigned e[8];
#pragma unroll
            for (int t = 0; t < 8; t++) e[t] = ej[idx + t];
            __half2 vh[8], th[8];
#pragma unroll
            for (int t = 0; t < 8; t++) {
                vh[t] = vp[(size_t)(e[t] >> 13) * 64 + lane];
                th[t] = Tn[(size_t)(e[t] & 8191u) * 64 + lane];
            }
            unsigned zw[8];
#pragma unroll
            for (int t = 0; t < 8; t++) {
                float2 vv = __half22float2(vh[t]);
                float2 tt = __half22float2(th[t]);
                float z0 = uu.x + vv.x + tt.x;
                float z1 = uu.y + vv.y + tt.y;
                __half2 zh = __floats2half2_rn(z0, z1);
                zw[t] = *(unsigned*)&zh;
                sx += z0; qx += z0 * z0;
                sy += z1; qy += z1 * z1;
            }
#pragma unroll
            for (int t = 0; t < 8; t += 2) {
                __builtin_nontemporal_store(pack64(zw[t], zw[t + 1]),
                    (unsigned long long*)&zbuf[zaddr(idx + t, lane)]);
            }
        }
        for (; idx + 2 <= re; idx += 2) {
            float z1a, z0a = z_of(vp, Tn, ej[idx], lane, uu, z1a);
            float z1b, z0b = z_of(vp, Tn, ej[idx + 1], lane, uu, z1b);
            __half2 ha = __floats2half2_rn(z0a, z1a);
            __half2 hb = __floats2half2_rn(z0b, z1b);
            __builtin_nontemporal_store(pack64(*(unsigned*)&ha, *(unsigned*)&hb),
                (unsigned long long*)&zbuf[zaddr(idx, lane)]);
            sx += z0a + z0b; qx += z0a * z0a + z0b * z0b;
            sy += z1a + z1b; qy += z1a * z1a + z1b * z1b;
        }
        if (idx < re) {
            float z1, z0 = z_of(vp, Tn, ej[idx], lane, uu, z1);
            __half2 zh = __floats2half2_rn(z0, z1);
            __builtin_nontemporal_store(*(unsigned*)&zh, &zbuf[zaddr(idx, lane)]);
            sx += z0; qx += z0 * z0; sy += z1; qy += z1 * z1;
        }
    }
    __shared__ float red[4][64][4];
    red[wv][lane][0] = sx; red[wv][lane][1] = sy;
    red[wv][lane][2] = qx; red[wv][lane][3] = qy;
    __syncthreads();
    if (wv == 0) {
        for (int r = 1; r < 4; r++) {
            sx += red[r][lane][0]; sy += red[r][lane][1];
            qx += red[r][lane][2]; qy += red[r][lane][3];
        }
        atomicAdd(&sums[lane], sx);
        atomicAdd(&sums[lane + 64], sy);
        atomicAdd(&sums[128 + lane], qx);
        atomicAdd(&sums[192 + lane], qy);
    }
}

// pass B: stream z (nt 64-bit loads, pair layout), inline BN fold,
// sigmoid*softplus, aggregate; LN + residual + softplus epilogue in shuffles.
__global__ void __launch_bounds__(256) k_aggz(
    const unsigned* __restrict__ zbuf, const int* __restrict__ rp,
    const float* __restrict__ sums,
    const float* __restrict__ bng, const float* __restrict__ bnb,
    const float* __restrict__ lng, const float* __restrict__ lnb,
    int l, const float* __restrict__ xin, float* __restrict__ xout) {
    int lane = threadIdx.x & 63;
    int wv = __builtin_amdgcn_readfirstlane(threadIdx.x >> 6);
    int i = blockIdx.x * 4 + wv;
    float mu1 = sums[lane] * (1.0f / EE);
    float var1 = sums[128 + lane] * (1.0f / EE) - mu1 * mu1;
    float A1 = rsqrtf(var1 + EPS) * bng[l * 128 + lane];
    float B1 = bnb[l * 128 + lane] - mu1 * A1;
    float mu2 = sums[64 + lane] * (1.0f / EE);
    float var2 = sums[192 + lane] * (1.0f / EE) - mu2 * mu2;
    float A2 = rsqrtf(var2 + EPS) * bng[l * 128 + 64 + lane];
    float B2 = bnb[l * 128 + 64 + lane] - mu2 * A2;

    float xr = xin[(size_t)i * 64 + lane];
    float acc = 0.f;
    int rs = __builtin_amdgcn_readfirstlane(rp[i]);
    int re = __builtin_amdgcn_readfirstlane(rp[i + 1]);
    int idx = rs;
    auto do1 = [&](unsigned zrw) {
        float2 z = __half22float2(*(const __half2*)&zrw);
        acc += sigmoid_fast(z.x * A1 + B1) * softplus_fast(z.y * A2 + B2);
    };
    if (idx < re && (idx & 1)) {
        do1(__builtin_nontemporal_load(&zbuf[zaddr(idx, lane)]));
        idx++;
    }
    for (; idx + 8 <= re; idx += 8) {
        unsigned long long zr[4];
#pragma unroll
        for (int t = 0; t < 4; t++)
            zr[t] = __builtin_nontemporal_load(
                (const unsigned long long*)&zbuf[zaddr(idx + 2 * t, lane)]);
#pragma unroll
        for (int t = 0; t < 4; t++) {
            do1((unsigned)zr[t]); do1((unsigned)(zr[t] >> 32));
        }
    }
    for (; idx + 2 <= re; idx += 2) {
        unsigned long long zr = __builtin_nontemporal_load(
            (const unsigned long long*)&zbuf[zaddr(idx, lane)]);
        do1((unsigned)zr); do1((unsigned)(zr >> 32));
    }
    if (idx < re) do1(__builtin_nontemporal_load(&zbuf[zaddr(idx, lane)]));

    float s = acc;
#pragma unroll
    for (int off = 32; off; off >>= 1) s += __shfl_xor(s, off, 64);
    float mean = s * (1.0f / 64.0f);
    float e0v = acc - mean;
    float vv2 = e0v * e0v;
#pragma unroll
    for (int off = 32; off; off >>= 1) vv2 += __shfl_xor(vv2, off, 64);
    float var = vv2 * (1.0f / 64.0f);
    float h = e0v * rsqrtf(var + EPS) * lng[l * 64 + lane] + lnb[l * 64 + lane];
    xout[(size_t)i * 64 + lane] = softplus_ref(h + xr);
}

// pass B fallback (ws too small): gather version with nearest-T
__global__ void __launch_bounds__(256) k_agg(
    const __half2* __restrict__ up, const __half2* __restrict__ vp,
    const __half2* __restrict__ Tn, const unsigned* __restrict__ ej,
    const int* __restrict__ rp, const float* __restrict__ sums,
    const float* __restrict__ bng, const float* __restrict__ bnb,
    const float* __restrict__ lng, const float* __restrict__ lnb,
    int l, const float* __restrict__ xin, float* __restrict__ xout) {
    int lane = threadIdx.x & 63;
    int wv = __builtin_amdgcn_readfirstlane(threadIdx.x >> 6);
    int i = blockIdx.x * 4 + wv;
    float mu1 = sums[lane] * (1.0f / EE);
    float var1 = sums[128 + lane] * (1.0f / EE) - mu1 * mu1;
    float A1 = rsqrtf(var1 + EPS) * bng[l * 128 + lane];
    float B1 = bnb[l * 128 + lane] - mu1 * A1;
    float mu2 = sums[64 + lane] * (1.0f / EE);
    float var2 = sums[192 + lane] * (1.0f / EE) - mu2 * mu2;
    float A2 = rsqrtf(var2 + EPS) * bng[l * 128 + 64 + lane];
    float B2 = bnb[l * 128 + 64 + lane] - mu2 * A2;

    float2 uu = __half22float2(up[(size_t)i * 64 + lane]);
    float xr = xin[(size_t)i * 64 + lane];
    float acc = 0.f;
    int rs = __builtin_amdgcn_readfirstlane(rp[i]);
    int re = __builtin_amdgcn_readfirstlane(rp[i + 1]);
    int idx = rs;
    for (; idx + 8 <= re; idx += 8) {
        unsigned e[8];
#pragma unroll
        for (int t = 0; t < 8; t++) e[t] = ej[idx + t];
        __half2 vh[8], th[8];
#pragma unroll
        for (int t = 0; t < 8; t++) {
            vh[t] = vp[(size_t)(e[t] >> 13) * 64 + lane];
            th[t] = Tn[(size_t)(e[t] & 8191u) * 64 + lane];
        }
#pragma unroll
        for (int t = 0; t < 8; t++) {
            float2 vv = __half22float2(vh[t]);
            float2 tt = __half22float2(th[t]);
            float z0 = (uu.x + vv.x + tt.x) * A1 + B1;
            float z1 = (uu.y + vv.y + tt.y) * A2 + B2;
            acc += sigmoid_fast(z0) * softplus_fast(z1);
        }
    }
    for (; idx < re; ++idx) {
        unsigned e = ej[idx];
        float2 vv = __half22float2(vp[(size_t)(e >> 13) * 64 + lane]);
        float2 tt = __half22float2(Tn[(size_t)(e & 8191u) * 64 + lane]);
        float z0 = (uu.x + vv.x + tt.x) * A1 + B1;
        float z1 = (uu.y + vv.y + tt.y) * A2 + B2;
        acc += sigmoid_fast(z0) * softplus_fast(z1);
    }
    float s = acc;
#pragma unroll
    for (int off = 32; off; off >>= 1) s += __shfl_xor(s, off, 64);
    float mean = s * (1.0f / 64.0f);
    float e0v = acc - mean;
    float vv2 = e0v * e0v;
#pragma unroll
    for (int off = 32; off; off >>= 1) vv2 += __shfl_xor(vv2, off, 64);
    float var = vv2 * (1.0f / 64.0f);
    float h = e0v * rsqrtf(var + EPS) * lng[l * 64 + lane] + lnb[l * 64 + lane];
    xout[(size_t)i * 64 + lane] = softplus_ref(h + xr);
}

// batch sorted -> graph row pointers by binary search
__global__ void k_gp(const int* __restrict__ batch, int* __restrict__ gp) {
    int g = threadIdx.x;
    if (g > GG) return;
    int lo = 0, hi = NN;
    while (lo < hi) {
        int mid = (lo + hi) >> 1;
        if (batch[mid] < g) lo = mid + 1; else hi = mid;
    }
    gp[g] = lo;
}

// atomic-free segmented mean-pool
__global__ void k_pool2(const float* __restrict__ x, const int* __restrict__ gp,
                        float* __restrict__ mols) {
    int g = blockIdx.x;
    int lane = threadIdx.x & 63, slot = threadIdx.x >> 6;
    int s0 = gp[g], s1 = gp[g + 1];
    float acc = 0.f;
    for (int n = s0 + slot; n < s1; n += 4) acc += x[(size_t)n * 64 + lane];
    __shared__ float red[4][64];
    red[slot][lane] = acc;
    __syncthreads();
    if (slot == 0) {
        float a = red[0][lane] + red[1][lane] + red[2][lane] + red[3][lane];
        float cc = fmaxf((float)(s1 - s0), 1.0f);
        mols[g * 64 + lane] = a / cc;
    }
}

__global__ void k_mlp(const float* __restrict__ mols,
                      const float* __restrict__ fc1W, const float* __restrict__ fc1b,
                      const float* __restrict__ fcsW, const float* __restrict__ fcsb,
                      const float* __restrict__ outW, const float* __restrict__ outb,
                      float* __restrict__ y) {
    int g = blockIdx.x, t = threadIdx.x; // 128 threads
    __shared__ float m[64];
    __shared__ float h[128];
    __shared__ float rbuf[128];
    if (t < 64) m[t] = mols[g * 64 + t];
    __syncthreads();
    float a = fc1b[t];
#pragma unroll 4
    for (int k = 0; k < 64; k++) a += m[k] * fc1W[k * 128 + t];
    h[t] = softplus_ref(a);
    __syncthreads();
    for (int i = 0; i < 3; i++) {
        float b = fcsb[i * 128 + t];
#pragma unroll 4
        for (int k = 0; k < 128; k++) b += h[k] * fcsW[((size_t)i * 128 + k) * 128 + t];
        __syncthreads();
        h[t] = softplus_ref(b);
        __syncthreads();
    }
    rbuf[t] = h[t] * outW[t];
    __syncthreads();
    if (t < 64) {
        float s2 = rbuf[t] + rbuf[t + 64];
#pragma unroll
        for (int off = 32; off; off >>= 1) s2 += __shfl_xor(s2, off, 64);
        if (t == 0) y[g] = s2 + outb[0];
    }
}

extern "C" void kernel_launch(void* const* d_in, const int* in_sizes, int n_in,
                              void* d_out, int out_size, void* d_ws, size_t ws_size,
                              hipStream_t stream) {
    const int*   an    = (const int*)d_in[0];
    const int*   nbr   = (const int*)d_in[1];
    const float* dist  = (const float*)d_in[2];
    const int*   batch = (const int*)d_in[3];
    const float* emb   = (const float*)d_in[4];
    const float* nucW  = (const float*)d_in[5];
    const float* nucB  = (const float*)d_in[6];
    const float* convW = (const float*)d_in[7];
    const float* convB = (const float*)d_in[8];
    const float* bng   = (const float*)d_in[9];
    const float* bnb   = (const float*)d_in[10];
    const float* lng   = (const float*)d_in[11];
    const float* lnb   = (const float*)d_in[12];
    const float* fc1W  = (const float*)d_in[13];
    const float* fc1b  = (const float*)d_in[14];
    const float* fcsW  = (const float*)d_in[15];
    const float* fcsb  = (const float*)d_in[16];
    const float* outW  = (const float*)d_in[17];
    const float* outb  = (const float*)d_in[18];
    const int* srcI = nbr;
    const int* dstI = nbr + EE;

    char* base = (char*)d_ws;
    size_t off = 0;
    auto alloc = [&](size_t b) { size_t r = off; off += (b + 255) & ~(size_t)255; return r; };
    float*    gtab   = (float*)(base + alloc((size_t)TS * 100 * 4));
    __half2*  Tall   = (__half2*)(base + alloc((size_t)6 * TS * 64 * 4));
    float4*   Wp     = (float4*)(base + alloc((size_t)6 * 64 * 64 * 16));
    float*    x0     = (float*)(base + alloc((size_t)NN * 64 * 4));
    float*    x1     = (float*)(base + alloc((size_t)NN * 64 * 4));
    __half2*  up     = (__half2*)(base + alloc((size_t)NN * 64 * 4));
    __half2*  vp     = (__half2*)(base + alloc((size_t)NN * 64 * 4));
    float*    sums6  = (float*)(base + alloc((size_t)6 * 256 * 4));
    int*      counts = (int*)(base + alloc((size_t)NN * 4));
    int*      cursor = (int*)(base + alloc((size_t)NN * 4));
    int*      rp     = (int*)(base + alloc((size_t)(NN + 1) * 4));
    int*      bsum   = (int*)(base + alloc(64 * 4));
    unsigned* ej     = (unsigned*)(base + alloc((size_t)EE * 4));
    float*    mols   = (float*)(base + alloc((size_t)GG * 64 * 4));
    int*      gp     = (int*)(base + alloc((size_t)(GG + 1) * 4));
    size_t zbytes = (size_t)(EE + 2) * 64 * 4;   // 128 MB fp16 channel-pairs (pair layout)
    unsigned* zbuf = nullptr;
    if (off + zbytes <= ws_size) zbuf = (unsigned*)(base + alloc(zbytes));

    hipMemsetAsync(counts, 0, (size_t)NN * 4, stream);
    hipMemsetAsync(cursor, 0, (size_t)NN * 4, stream);
    hipMemsetAsync(sums6, 0, (size_t)6 * 256 * 4, stream);

    k_gtab<<<(TS * 100 + 255) / 256, 256, 0, stream>>>(gtab);
    k_build_T<<<dim3(TS / 16, 6), 256, 0, stream>>>(gtab, convW, convB, Tall);
    k_prepW<<<dim3(64, 6), 64, 0, stream>>>(convW, Wp);
    k_embed<<<(NN + 3) / 4, 256, 0, stream>>>(an, emb, nucW, nucB, x0);
    k_hist<<<(EE + 255) / 256, 256, 0, stream>>>(dstI, counts);
    const int NB = (NN + 1023) / 1024;
    k_scan_local<<<NB, 1024, 0, stream>>>(counts, rp, bsum);
    k_scan_off<<<1, 64, 0, stream>>>(bsum, NB);
    k_scan_add<<<NB, 1024, 0, stream>>>(rp, bsum);
    k_scatter<<<(EE + 255) / 256, 256, 0, stream>>>(srcI, dstI, dist, rp, cursor, ej);
    k_gp<<<1, 128, 0, stream>>>(batch, gp);

    float* xin = x0;
    float* xout = x1;
    for (int l = 0; l < 6; l++) {
        k_uv<<<NN / 16, 256, 0, stream>>>(xin, Wp + (size_t)l * 64 * 64, up, vp);
        const __half2* Tnl = Tall + (size_t)l * TS * 64;
        float* sums = sums6 + (size_t)l * 256;
        k_stats<<<2048, 256, 0, stream>>>(up, vp, Tnl, ej, rp, sums, zbuf);
        if (zbuf)
            k_aggz<<<NN / 4, 256, 0, stream>>>(zbuf, rp, sums,
                                               bng, bnb, lng, lnb, l, xin, xout);
        else
            k_agg<<<NN / 4, 256, 0, stream>>>(up, vp, Tnl, ej, rp, sums,
                                              bng, bnb, lng, lnb, l, xin, xout);
        float* tmp = xin; xin = xout; xout = tmp;
    }
    k_pool2<<<GG, 256, 0, stream>>>(xin, gp, mols);
    k_mlp<<<GG, 128, 0, stream>>>(mols, fc1W, fc1b, fcsW, fcsb, outW, outb, (float*)d_out);
}